// Round 11
// baseline (421.335 us; speedup 1.0000x reference)
//
#include <hip/hip_runtime.h>
#include <stdint.h>

#define Bb 32
#define Nn 256
#define Ee 8
#define Ff 16
#define K1 32

typedef unsigned long long u64;
typedef float f32x4 __attribute__((ext_vector_type(4)));

// Kernel A: adjacency floats -> 256-bit row bitmasks. One wave per (b,r).
__global__ void bitmask_kernel(const float* __restrict__ adj, u64* __restrict__ bm) {
    int wave = (blockIdx.x << 2) + (threadIdx.x >> 6);   // (b*N + r), 4 waves/block
    int lane = threadIdx.x & 63;
    const float* row = adj + (size_t)wave * Nn;
#pragma unroll
    for (int w = 0; w < 4; ++w) {
        float v = row[w * 64 + lane];
        u64 m = __ballot(v != 0.0f);
        if (lane == 0) bm[(size_t)wave * 4 + w] = m;
    }
}

// Kernel B2: wave-parallel BFS, one WAVE per start vertex. 2048 blocks x 256.
// Branch-free enqueue: position = count + popc(prefix bits). Also emits the
// 32x32 submask per start (16 ballots).
__global__ void bfs2_kernel(const u64* __restrict__ bm,
                            uint32_t* __restrict__ proc32,
                            uint32_t* __restrict__ submask_g) {
    __shared__ u64 bml[Nn * 4];              // 8 KB: batch bitmask rows
    __shared__ uint8_t order[4][K1];         // per-wave BFS queue
    __shared__ uint32_t subm[4][K1];         // per-wave 32x32 submask
    int blk = blockIdx.x;
    int b = blk >> 6;                        // 64 blocks per batch
    int t = threadIdx.x;
    int wv = t >> 6, l = t & 63;

#pragma unroll
    for (int k = 0; k < 4; ++k) bml[t + k * 256] = bm[(size_t)b * 1024 + t + k * 256];
    __syncthreads();

    int s = ((blk & 63) << 2) + wv;          // this wave's start vertex
    u64 seen[4];
#pragma unroll
    for (int q = 0; q < 4; ++q) seen[q] = (q == (s >> 6)) ? (1ull << (s & 63)) : 0ull;
    if (l == 0) order[wv][0] = (uint8_t)s;
    u64 lpre = (1ull << l) - 1ull;           // prefix mask for this lane
    int count = 1;                           // wave-uniform
    for (int i = 0; i < K1; ++i) {
        int cur = order[wv][i];              // uniform LDS read (same wave wrote it)
#pragma unroll
        for (int q = 0; q < 4; ++q) {
            u64 nw = bml[cur * 4 + q] & ~seen[q];
            seen[q] |= nw;
            int pos = count + __popcll(nw & lpre);
            if (((nw >> l) & 1ull) && pos < K1)
                order[wv][pos] = (uint8_t)((q << 6) + l);
            count += __popcll(nw);           // uniform
        }
        if (count >= K1) break;              // order[0..31] is final
    }

    // 32x32 submask: 16 ballot steps, 2 rows per step (lanes 0-31 / 32-63)
    int half = l >> 5, j2 = l & 31;
#pragma unroll
    for (int step = 0; step < 16; ++step) {
        int row = order[wv][step * 2 + half];
        int pj = order[wv][j2];
        bool bit = (bml[row * 4 + (pj >> 6)] >> (pj & 63)) & 1ull;
        u64 bal = __ballot(bit);
        if (l == 0)  subm[wv][step * 2]     = (uint32_t)bal;
        if (l == 32) subm[wv][step * 2 + 1] = (uint32_t)(bal >> 32);
    }

    // coalesced writeout
    const uint32_t* o32 = (const uint32_t*)&order[wv][0];
    if (l < 8) proc32[((size_t)b * 256 + s) * 8 + l] = o32[l];
    if (l < 32) submask_g[((size_t)b * 256 + s) * 32 + l] = subm[wv][l];
}

// Kernel C: gather all three outputs. One block per (b,s). R8 body with
// T14-style reorder: issue the 8 conditional edge loads FIRST, then the
// independent out0/out2 stores (hide load latency), then the edge stores.
__global__ void gather_kernel(const f32x4* __restrict__ e4,
                              const f32x4* __restrict__ feats4,
                              const uint32_t* __restrict__ proc32,
                              const uint32_t* __restrict__ submask_g,
                              float* __restrict__ out) {
    int bs = blockIdx.x;
    int b = bs >> 8;
    int t = threadIdx.x;
    __shared__ int p[K1];
    __shared__ uint32_t sm[K1];

    if (t < 8) {
        uint32_t w = proc32[(size_t)bs * 8 + t];
        p[t * 4 + 0] = w & 255;
        p[t * 4 + 1] = (w >> 8) & 255;
        p[t * 4 + 2] = (w >> 16) & 255;
        p[t * 4 + 3] = (w >> 24) & 255;
    }
    if (t >= 64 && t < 96) sm[t - 64] = submask_g[(size_t)bs * 32 + (t - 64)];
    __syncthreads();

    // ---- issue the 8 conditional edge loads up front ----
    f32x4 vals[8];
    uint32_t active = 0;
#pragma unroll
    for (int k = 0; k < 8; ++k) {
        int v = t + k * 256;
        int i = v >> 6, j = (v >> 1) & 31, h = v & 1;
        bool m = (sm[i] >> j) & 1u;
        active |= (uint32_t)m << k;
        if (m) vals[k] = e4[(((size_t)b * 256 + p[i]) * 256 + p[j]) * 2 + h];
    }

    // ---- sub_adj: (K1,K1) floats, 256 f32x4 per block (independent) ----
    f32x4* out0 = (f32x4*)(out) + (size_t)bs * 256;
    {
        int i = t >> 3;
        int j0 = (t & 7) * 4;
        uint32_t m = sm[i];
        f32x4 a;
        a.x = (float)((m >> (j0 + 0)) & 1u);
        a.y = (float)((m >> (j0 + 1)) & 1u);
        a.z = (float)((m >> (j0 + 2)) & 1u);
        a.w = (float)((m >> (j0 + 3)) & 1u);
        out0[t] = a;
    }

    // ---- sub_feats: (K1,F) floats, 128 f32x4 per block (independent) ----
    f32x4* out2 = (f32x4*)(out + 75497472ull) + (size_t)bs * 128;
    if (t < 128) {
        int i = t >> 2, f4 = t & 3;
        out2[t] = feats4[((size_t)b * 256 + p[i]) * 4 + f4];
    }

    // ---- sub_edges stores (loads should have landed by now) ----
    f32x4* out1 = (f32x4*)(out + 8388608ull) + (size_t)bs * 2048;
    f32x4 z = (f32x4){0.f, 0.f, 0.f, 0.f};
#pragma unroll
    for (int k = 0; k < 8; ++k) {
        int v = t + k * 256;
        out1[v] = ((active >> k) & 1u) ? vals[k] : z;
    }
}

extern "C" void kernel_launch(void* const* d_in, const int* in_sizes, int n_in,
                              void* d_out, int out_size, void* d_ws, size_t ws_size,
                              hipStream_t stream) {
    const float* adj   = (const float*)d_in[0];
    const float* edges = (const float*)d_in[1];
    const float* feats = (const float*)d_in[2];
    float* out = (float*)d_out;

    u64* bm = (u64*)d_ws;                                       // 256 KB
    uint32_t* proc32  = (uint32_t*)((char*)d_ws + (256 << 10)); // 256 KB
    uint32_t* submask = (uint32_t*)((char*)d_ws + (512 << 10)); // 1 MB

    bitmask_kernel<<<Bb * Nn / 4, 256, 0, stream>>>(adj, bm);
    bfs2_kernel<<<2048, 256, 0, stream>>>(bm, proc32, submask);
    gather_kernel<<<Bb * Nn, 256, 0, stream>>>((const f32x4*)edges, (const f32x4*)feats,
                                               proc32, submask, out);
}

// Round 12
// 79.252 us; speedup vs baseline: 5.3164x; 5.3164x over previous
//
#include <hip/hip_runtime.h>
#include <stdint.h>

#define Bb 32
#define Nn 256
#define Ee 8
#define Ff 16
#define K1 32

typedef unsigned long long u64;
typedef float f32x4 __attribute__((ext_vector_type(4)));

// Kernel A: adjacency floats -> 256-bit row bitmasks. One wave per (b,r).
__global__ void bitmask_kernel(const float* __restrict__ adj, u64* __restrict__ bm) {
    int wave = (blockIdx.x << 2) + (threadIdx.x >> 6);   // (b*N + r), 4 waves/block
    int lane = threadIdx.x & 63;
    const float* row = adj + (size_t)wave * Nn;
#pragma unroll
    for (int w = 0; w < 4; ++w) {
        float v = row[w * 64 + lane];
        u64 m = __ballot(v != 0.0f);
        if (lane == 0) bm[(size_t)wave * 4 + w] = m;
    }
}

// Kernel B2: wave-parallel BFS, one WAVE per start vertex. 2048 blocks x 256.
// Branch-free enqueue: position = count + popc(prefix bits). Also emits the
// 32x32 submask per start (16 ballots) so kernel C needs no scattered gathers.
__global__ void bfs2_kernel(const u64* __restrict__ bm,
                            uint32_t* __restrict__ proc32,
                            uint32_t* __restrict__ submask_g) {
    __shared__ u64 bml[Nn * 4];              // 8 KB: batch bitmask rows
    __shared__ uint8_t order[4][K1];         // per-wave BFS queue
    __shared__ uint32_t subm[4][K1];         // per-wave 32x32 submask
    int blk = blockIdx.x;
    int b = blk >> 6;                        // 64 blocks per batch
    int t = threadIdx.x;
    int wv = t >> 6, l = t & 63;

#pragma unroll
    for (int k = 0; k < 4; ++k) bml[t + k * 256] = bm[(size_t)b * 1024 + t + k * 256];
    __syncthreads();

    int s = ((blk & 63) << 2) + wv;          // this wave's start vertex
    u64 seen[4];
#pragma unroll
    for (int q = 0; q < 4; ++q) seen[q] = (q == (s >> 6)) ? (1ull << (s & 63)) : 0ull;
    if (l == 0) order[wv][0] = (uint8_t)s;
    u64 lpre = (1ull << l) - 1ull;           // prefix mask for this lane
    int count = 1;                           // wave-uniform
    for (int i = 0; i < K1; ++i) {
        int cur = order[wv][i];              // uniform LDS read (same wave wrote it)
#pragma unroll
        for (int q = 0; q < 4; ++q) {
            u64 nw = bml[cur * 4 + q] & ~seen[q];
            seen[q] |= nw;
            int pos = count + __popcll(nw & lpre);
            if (((nw >> l) & 1ull) && pos < K1)
                order[wv][pos] = (uint8_t)((q << 6) + l);
            count += __popcll(nw);           // uniform
        }
        if (count >= K1) break;              // order[0..31] is final
    }

    // 32x32 submask: 16 ballot steps, 2 rows per step (lanes 0-31 / 32-63)
    int half = l >> 5, j2 = l & 31;
#pragma unroll
    for (int step = 0; step < 16; ++step) {
        int row = order[wv][step * 2 + half];
        int pj = order[wv][j2];
        bool bit = (bml[row * 4 + (pj >> 6)] >> (pj & 63)) & 1ull;
        u64 bal = __ballot(bit);
        if (l == 0)  subm[wv][step * 2]     = (uint32_t)bal;
        if (l == 32) subm[wv][step * 2 + 1] = (uint32_t)(bal >> 32);
    }

    // coalesced writeout
    const uint32_t* o32 = (const uint32_t*)&order[wv][0];
    if (l < 8) proc32[((size_t)b * 256 + s) * 8 + l] = o32[l];
    if (l < 32) submask_g[((size_t)b * 256 + s) * 32 + l] = subm[wv][l];
}

// Kernel C: gather all three outputs. One block per (b,s). R8-exact body:
// interleaved conditional load -> store per k (<=1 edge value live; no spill).
__global__ void gather_kernel(const f32x4* __restrict__ e4,
                              const f32x4* __restrict__ feats4,
                              const uint32_t* __restrict__ proc32,
                              const uint32_t* __restrict__ submask_g,
                              float* __restrict__ out) {
    int bs = blockIdx.x;
    int b = bs >> 8;
    int t = threadIdx.x;
    __shared__ int p[K1];
    __shared__ uint32_t sm[K1];

    if (t < 8) {
        uint32_t w = proc32[(size_t)bs * 8 + t];
        p[t * 4 + 0] = w & 255;
        p[t * 4 + 1] = (w >> 8) & 255;
        p[t * 4 + 2] = (w >> 16) & 255;
        p[t * 4 + 3] = (w >> 24) & 255;
    }
    if (t >= 64 && t < 96) sm[t - 64] = submask_g[(size_t)bs * 32 + (t - 64)];
    __syncthreads();

    // ---- sub_adj: (K1,K1) floats, 256 f32x4 per block ----
    f32x4* out0 = (f32x4*)(out) + (size_t)bs * 256;
    {
        int i = t >> 3;
        int j0 = (t & 7) * 4;
        uint32_t m = sm[i];
        f32x4 a;
        a.x = (float)((m >> (j0 + 0)) & 1u);
        a.y = (float)((m >> (j0 + 1)) & 1u);
        a.z = (float)((m >> (j0 + 2)) & 1u);
        a.w = (float)((m >> (j0 + 3)) & 1u);
        out0[t] = a;
    }

    // ---- sub_feats: (K1,F) floats, 128 f32x4 per block ----
    f32x4* out2 = (f32x4*)(out + 75497472ull) + (size_t)bs * 128;
    if (t < 128) {
        int i = t >> 2, f4 = t & 3;
        out2[t] = feats4[((size_t)b * 256 + p[i]) * 4 + f4];
    }

    // ---- sub_edges: (K1,K1,E) floats, 2048 f32x4 per block ----
    f32x4* out1 = (f32x4*)(out + 8388608ull) + (size_t)bs * 2048;
#pragma unroll
    for (int k = 0; k < 8; ++k) {
        int v = t + k * 256;
        int i = v >> 6, j = (v >> 1) & 31, h = v & 1;
        bool m = (sm[i] >> j) & 1u;
        f32x4 val = (f32x4){0.f, 0.f, 0.f, 0.f};
        if (m) val = e4[(((size_t)b * 256 + p[i]) * 256 + p[j]) * 2 + h];
        out1[v] = val;
    }
}

extern "C" void kernel_launch(void* const* d_in, const int* in_sizes, int n_in,
                              void* d_out, int out_size, void* d_ws, size_t ws_size,
                              hipStream_t stream) {
    const float* adj   = (const float*)d_in[0];
    const float* edges = (const float*)d_in[1];
    const float* feats = (const float*)d_in[2];
    float* out = (float*)d_out;

    u64* bm = (u64*)d_ws;                                       // 256 KB
    uint32_t* proc32  = (uint32_t*)((char*)d_ws + (256 << 10)); // 256 KB
    uint32_t* submask = (uint32_t*)((char*)d_ws + (512 << 10)); // 1 MB

    bitmask_kernel<<<Bb * Nn / 4, 256, 0, stream>>>(adj, bm);
    bfs2_kernel<<<2048, 256, 0, stream>>>(bm, proc32, submask);
    gather_kernel<<<Bb * Nn, 256, 0, stream>>>((const f32x4*)edges, (const f32x4*)feats,
                                               proc32, submask, out);
}